// Round 7
// baseline (199.131 us; speedup 1.0000x reference)
//
#include <hip/hip_runtime.h>
#include <math.h>

// ---------------------------------------------------------------------------
// StatePerturbationEncoder, R7: 5 dispatches (prep + 4 GEMMs).
//  * BN handled on the A-side: each GEMM block recomputes scale/shift from
//    the previous layer's sharded stats (cheap, redundant) and applies the
//    affine while staging A into LDS -> no weight-fold kernels at all.
//  * 1024 blocks x 32 rows, __launch_bounds__(256,4) -> 16 waves/CU (R6 had
//    8) to hide the direct-global B-fragment latency (~200cyc L2).
//  * K-loop barrier-free, compiler-managed hazards (R6-validated).
// ---------------------------------------------------------------------------

typedef __attribute__((ext_vector_type(8))) short short8;   // 8 x bf16
typedef __attribute__((ext_vector_type(4))) float floatx4;  // MFMA acc

#define DDIM 256

__device__ __forceinline__ unsigned short f2bf(float f) {
    union { float f; unsigned int u; } v; v.f = f;
    unsigned int r = v.u + 0x7fffu + ((v.u >> 16) & 1u);   // RNE
    return (unsigned short)(r >> 16);
}
__device__ __forceinline__ float bf2f(unsigned short u) {
    union { unsigned int i; float f; } v; v.i = ((unsigned int)u) << 16;
    return v.f;
}
__device__ __forceinline__ float gelu_fast(float x) {
    // tanh-approx GELU, branchless (validated: absmax 0.023 vs 0.076 thr)
    float z = 0.7978845608f * (x + 0.044715f * x * x * x);
    float e = __expf(2.0f * z);
    float th = 1.0f - 2.0f * __builtin_amdgcn_rcpf(1.0f + e);
    return 0.5f * x * (1.0f + th);
}

// ---------------------------------------------------------------------------
// K0: transpose+cast all four W -> Wt (bf16 [n][k]); zero the stat shards.
// grid 1024: block b handles row n=(b&255) of W[b>>8].
// ---------------------------------------------------------------------------
__global__ void prep_kernel(const float* __restrict__ W0,
                            const float* __restrict__ W1,
                            const float* __restrict__ W2,
                            const float* __restrict__ W3,
                            unsigned short* __restrict__ Wt /* 4*65536 */,
                            float* __restrict__ stats /* 12288 f32 */)
{
    const int t = threadIdx.x, b = blockIdx.x;
    const int j = b >> 8, n = b & 255;
    const float* W = (j == 0) ? W0 : (j == 1) ? W1 : (j == 2) ? W2 : W3;
    // read row n of W coalesced; scatter into column n of Wt[j]
    Wt[((size_t)j << 16) + (size_t)t * DDIM + n] = f2bf(W[(size_t)n * DDIM + t]);
    if (b < 12) {
        float* s = stats + b * 1024;
        s[t] = 0.f; s[t + 256] = 0.f; s[t + 512] = 0.f; s[t + 768] = 0.f;
    }
}

// ---------------------------------------------------------------------------
// GEMM: out = GELU( BN?(A) @ Wt^T + bias ). A: bf16 acts (or gathered fp32
// table rows when GATHER). Block = 32 rows x 256 cols; wave wn owns cols
// wn*64..+63, 2x4 grid of 16x16x32 MFMAs. AFFINE: per-column y*scl+shf
// (BN of previous layer) applied while staging A. DO_STATS: column sum/sumsq
// of GELU output -> 8-way sharded device accumulators.
// ---------------------------------------------------------------------------
template<int GATHER, int AFFINE, int WRITE_F32, int DO_STATS>
__global__ __launch_bounds__(256, 4)
void gemm_enc(const unsigned short* __restrict__ A,
              const int* __restrict__ ids,
              const float* __restrict__ table,
              const unsigned short* __restrict__ Wt,
              const float* __restrict__ bias,
              const float* __restrict__ statsIn,
              const float* __restrict__ gma,
              const float* __restrict__ bta,
              void* __restrict__ outp,
              float* __restrict__ statShards)
{
    // A panel [32 r][32 granules of 8 bf16]; granule g of row r at slot
    // g^(r&7) (R2/R4/R6-validated conflict-free frag reads).
    __shared__ alignas(16) unsigned short Albs[32 * 256];    // 16 KB
    __shared__ float sc[256], sh[256];                       // 2 KB

    const int tid  = threadIdx.x;
    const int blk  = blockIdx.x;
    const int wave = tid >> 6;
    const int lane = tid & 63;
    const int quad = lane >> 4;
    const int l15  = lane & 15;
    const int wn   = wave;
    const int row0 = blk * 32;

    if (AFFINE) {
        // thread t -> column t: finalize BN stats of the previous layer
        float sum = 0.f, sq = 0.f;
#pragma unroll
        for (int s = 0; s < 8; ++s) {
            sum += statsIn[s * 512 + tid];
            sq  += statsIn[s * 512 + 256 + tid];
        }
        const float mu  = sum * (1.f / 32768.f);
        const float var = sq * (1.f / 32768.f) - mu * mu;
        const float scl = rsqrtf(var + 1e-5f) * gma[tid];
        sc[tid] = scl;
        sh[tid] = bta[tid] - mu * scl;
        __syncthreads();
    }

    // ---- stage A panel: thread t -> row t&31, 32-col chunk (t>>5)*32 ----
    // (chunk-major per wave so sc/sh reads are 2-way broadcast, free)
    {
        const int r  = tid & 31;
        const int ci = tid >> 5;
        const int c0 = ci * 32;
        if (GATHER) {
            const int src = ids[row0 + r];
            const float* tp = table + (size_t)src * DDIM + c0;
#pragma unroll
            for (int j = 0; j < 4; ++j) {
                float4 v0 = *(const float4*)(tp + j * 8);
                float4 v1 = *(const float4*)(tp + j * 8 + 4);
                union { unsigned short u[8]; uint4 v; } o;
                o.u[0]=f2bf(v0.x); o.u[1]=f2bf(v0.y); o.u[2]=f2bf(v0.z); o.u[3]=f2bf(v0.w);
                o.u[4]=f2bf(v1.x); o.u[5]=f2bf(v1.y); o.u[6]=f2bf(v1.z); o.u[7]=f2bf(v1.w);
                const int g = ci * 4 + j;
                *(uint4*)(Albs + r * 256 + (g ^ (r & 7)) * 8) = o.v;
            }
        } else {
            const unsigned short* ap = A + (size_t)(row0 + r) * DDIM + c0;
#pragma unroll
            for (int j = 0; j < 4; ++j) {
                union { unsigned short u[8]; uint4 v; } o;
                o.v = *(const uint4*)(ap + j * 8);
                if (AFFINE) {
#pragma unroll
                    for (int e = 0; e < 8; ++e) {
                        const int c = c0 + j * 8 + e;
                        o.u[e] = f2bf(fmaf(bf2f(o.u[e]), sc[c], sh[c]));
                    }
                }
                const int g = ci * 4 + j;
                *(uint4*)(Albs + r * 256 + (g ^ (r & 7)) * 8) = o.v;
            }
        }
    }

    float bias_v[4];
#pragma unroll
    for (int nt = 0; nt < 4; ++nt)
        bias_v[nt] = bias[wn * 64 + nt * 16 + l15];

    floatx4 acc[2][4];
#pragma unroll
    for (int i = 0; i < 2; ++i)
#pragma unroll
        for (int j = 0; j < 4; ++j)
            acc[i][j] = floatx4{0.f, 0.f, 0.f, 0.f};

    __syncthreads();   // A panel visible to all waves

    // ---- K loop: B frags straight from global (L2-hot), A from LDS ----
    const unsigned short* wb = Wt + (size_t)(wn * 64 + l15) * DDIM + quad * 8;
#pragma unroll 2
    for (int kk = 0; kk < 8; ++kk) {
        short8 bfr[4];
#pragma unroll
        for (int nt = 0; nt < 4; ++nt)
            bfr[nt] = *(const short8*)(wb + (size_t)(nt * 16) * DDIM + kk * 32);
        short8 af[2];
        const int agp = ((kk * 4 + quad) ^ (l15 & 7)) * 8;
#pragma unroll
        for (int mt = 0; mt < 2; ++mt)
            af[mt] = *(const short8*)(Albs + (mt * 16 + l15) * 256 + agp);
#pragma unroll
        for (int mt = 0; mt < 2; ++mt)
#pragma unroll
            for (int nt = 0; nt < 4; ++nt)
                acc[mt][nt] = __builtin_amdgcn_mfma_f32_16x16x32_bf16(
                    af[mt], bfr[nt], acc[mt][nt], 0, 0, 0);
    }

    // ---- epilogue: bias + GELU + store (+ sharded column stats) ----
    float s1[4] = {0.f, 0.f, 0.f, 0.f};
    float s2[4] = {0.f, 0.f, 0.f, 0.f};
#pragma unroll
    for (int mt = 0; mt < 2; ++mt) {
        const int rb = row0 + mt * 16 + quad * 4;            // C/D row=quad*4+reg
#pragma unroll
        for (int nt = 0; nt < 4; ++nt) {
            const int col = wn * 64 + nt * 16 + l15;         // C/D col=lane&15
#pragma unroll
            for (int i = 0; i < 4; ++i) {
                float y = gelu_fast(acc[mt][nt][i] + bias_v[nt]);
                if (WRITE_F32) {
                    ((float*)outp)[(size_t)(rb + i) * DDIM + col] = y;
                } else {
                    ((unsigned short*)outp)[(size_t)(rb + i) * DDIM + col] = f2bf(y);
                }
                if (DO_STATS) { s1[nt] += y; s2[nt] += y * y; }
            }
        }
    }
    if (DO_STATS) {
#pragma unroll
        for (int nt = 0; nt < 4; ++nt) {   // reduce the 4 quads (same column)
            s1[nt] += __shfl_xor(s1[nt], 16); s1[nt] += __shfl_xor(s1[nt], 32);
            s2[nt] += __shfl_xor(s2[nt], 16); s2[nt] += __shfl_xor(s2[nt], 32);
        }
        float* sb = statShards + (blk & 7) * 512;            // 8-way shard
        if (quad == 0) {
#pragma unroll
            for (int nt = 0; nt < 4; ++nt) {
                const int col = wn * 64 + nt * 16 + l15;
                atomicAdd(&sb[col],       s1[nt]);
                atomicAdd(&sb[256 + col], s2[nt]);
            }
        }
    }
}

// ---------------------------------------------------------------------------
extern "C" void kernel_launch(void* const* d_in, const int* in_sizes, int n_in,
                              void* d_out, int out_size, void* d_ws, size_t ws_size,
                              hipStream_t stream)
{
    const int*   ids   = (const int*)  d_in[0];
    const float* table = (const float*)d_in[1];
    const float* W1 = (const float*)d_in[2];  const float* b1 = (const float*)d_in[3];
    const float* W2 = (const float*)d_in[4];  const float* b2 = (const float*)d_in[5];
    const float* W3 = (const float*)d_in[6];  const float* b3 = (const float*)d_in[7];
    const float* W4 = (const float*)d_in[8];  const float* b4 = (const float*)d_in[9];
    const float* g1 = (const float*)d_in[10]; const float* be1 = (const float*)d_in[11];
    const float* g2 = (const float*)d_in[12]; const float* be2 = (const float*)d_in[13];
    const float* g3 = (const float*)d_in[14]; const float* be3 = (const float*)d_in[15];

    unsigned char* ws = (unsigned char*)d_ws;
    unsigned short* Wt   = (unsigned short*)ws;                      // 512 KiB
    float* stats = (float*)(ws + (size_t)524288);                    // 48 KiB
    unsigned short* act1 = (unsigned short*)(ws + (size_t)1048576);  // 16 MiB
    unsigned short* act2 = (unsigned short*)(ws + (size_t)17825792); // 16 MiB
    unsigned short* Wt1 = Wt;
    unsigned short* Wt2 = Wt + 65536;
    unsigned short* Wt3 = Wt + 131072;
    unsigned short* Wt4 = Wt + 196608;

    prep_kernel<<<1024, 256, 0, stream>>>(W1, W2, W3, W4, Wt, stats);

    gemm_enc<1, 0, 0, 1><<<1024, 256, 0, stream>>>(
        nullptr, ids, table, Wt1, b1, nullptr, nullptr, nullptr, act1, stats);
    gemm_enc<0, 1, 0, 1><<<1024, 256, 0, stream>>>(
        act1, nullptr, nullptr, Wt2, b2, stats, g1, be1, act2, stats + 4096);
    gemm_enc<0, 1, 0, 1><<<1024, 256, 0, stream>>>(
        act2, nullptr, nullptr, Wt3, b3, stats + 4096, g2, be2, act1, stats + 8192);
    gemm_enc<0, 1, 1, 0><<<1024, 256, 0, stream>>>(
        act1, nullptr, nullptr, Wt4, b4, stats + 8192, g3, be3, (void*)d_out, nullptr);
}

// Round 8
// 181.687 us; speedup vs baseline: 1.0960x; 1.0960x over previous
//
#include <hip/hip_runtime.h>
#include <math.h>

// ---------------------------------------------------------------------------
// StatePerturbationEncoder, R8: 5 dispatches (prep + 4 GEMMs).
//  * GEMM shape = R6's proven 64m x 256n, 512 blocks, launch_bounds(256,2)
//    (R7's 32-row tile regressed: halved MFMA-per-B-load, doubled B traffic).
//  * BN affine applied on the A-side during staging (R7-validated) -> no
//    fold kernels.
//  * K-loop: manual 1-deep software pipeline (preload kk+1 A/B frags before
//    kk's MFMAs) to cover ~200cyc L2 B-load latency; no barriers, all
//    hazards compiler-managed (R5's manual vmcnt protocol stays dead).
// ---------------------------------------------------------------------------

typedef __attribute__((ext_vector_type(8))) short short8;   // 8 x bf16
typedef __attribute__((ext_vector_type(4))) float floatx4;  // MFMA acc

#define DDIM 256

__device__ __forceinline__ unsigned short f2bf(float f) {
    union { float f; unsigned int u; } v; v.f = f;
    unsigned int r = v.u + 0x7fffu + ((v.u >> 16) & 1u);   // RNE
    return (unsigned short)(r >> 16);
}
__device__ __forceinline__ float bf2f(unsigned short u) {
    union { unsigned int i; float f; } v; v.i = ((unsigned int)u) << 16;
    return v.f;
}
__device__ __forceinline__ float gelu_fast(float x) {
    // tanh-approx GELU, branchless (validated: absmax 0.023 vs 0.076 thr)
    float z = 0.7978845608f * (x + 0.044715f * x * x * x);
    float e = __expf(2.0f * z);
    float th = 1.0f - 2.0f * __builtin_amdgcn_rcpf(1.0f + e);
    return 0.5f * x * (1.0f + th);
}

// ---------------------------------------------------------------------------
// K0: transpose+cast all four W -> Wt (bf16 [n][k]); zero the stat shards.
// grid 1024: block b handles row n=(b&255) of W[b>>8].
// ---------------------------------------------------------------------------
__global__ void prep_kernel(const float* __restrict__ W0,
                            const float* __restrict__ W1,
                            const float* __restrict__ W2,
                            const float* __restrict__ W3,
                            unsigned short* __restrict__ Wt /* 4*65536 */,
                            float* __restrict__ stats /* 12288 f32 */)
{
    const int t = threadIdx.x, b = blockIdx.x;
    const int j = b >> 8, n = b & 255;
    const float* W = (j == 0) ? W0 : (j == 1) ? W1 : (j == 2) ? W2 : W3;
    Wt[((size_t)j << 16) + (size_t)t * DDIM + n] = f2bf(W[(size_t)n * DDIM + t]);
    if (b < 12) {
        float* s = stats + b * 1024;
        s[t] = 0.f; s[t + 256] = 0.f; s[t + 512] = 0.f; s[t + 768] = 0.f;
    }
}

// ---------------------------------------------------------------------------
// GEMM: out = GELU( BN?(A) @ Wt^T + bias ). Block = 64 rows x 256 cols;
// wave wn owns cols wn*64..+63, 4x4 grid of 16x16x32 MFMAs. AFFINE applies
// the previous layer's BN (recomputed from sharded stats) during A staging.
// DO_STATS: column sum/sumsq of GELU output -> 8-way sharded accumulators.
// ---------------------------------------------------------------------------
template<int GATHER, int AFFINE, int WRITE_F32, int DO_STATS>
__global__ __launch_bounds__(256, 2)
void gemm_enc(const unsigned short* __restrict__ A,
              const int* __restrict__ ids,
              const float* __restrict__ table,
              const unsigned short* __restrict__ Wt,
              const float* __restrict__ bias,
              const float* __restrict__ statsIn,
              const float* __restrict__ gma,
              const float* __restrict__ bta,
              void* __restrict__ outp,
              float* __restrict__ statShards)
{
    // A panel [64 r][32 granules of 8 bf16]; granule g of row r at slot
    // g^(r&7) (R2/R4/R6-validated conflict-free frag reads).
    __shared__ alignas(16) unsigned short Albs[64 * 256];    // 32 KB
    __shared__ float sc[256], sh[256];                       // 2 KB

    const int tid  = threadIdx.x;
    const int blk  = blockIdx.x;
    const int wave = tid >> 6;
    const int lane = tid & 63;
    const int quad = lane >> 4;
    const int l15  = lane & 15;
    const int wn   = wave;
    const int row0 = blk * 64;

    if (AFFINE) {
        // thread t -> column t: finalize BN stats of the previous layer
        float sum = 0.f, sq = 0.f;
#pragma unroll
        for (int s = 0; s < 8; ++s) {
            sum += statsIn[s * 512 + tid];
            sq  += statsIn[s * 512 + 256 + tid];
        }
        const float mu  = sum * (1.f / 32768.f);
        const float var = sq * (1.f / 32768.f) - mu * mu;
        const float scl = rsqrtf(var + 1e-5f) * gma[tid];
        sc[tid] = scl;
        sh[tid] = bta[tid] - mu * scl;
        __syncthreads();   // sc/sh visible before staging uses them
    }

    // ---- stage A panel (thread t: row t>>2, 64-col chunk (t&3)*64) ----
    {
        const int r  = tid >> 2;
        const int c0 = (tid & 3) * 64;
        if (GATHER) {
            const int src = ids[row0 + r];
            const float* tp = table + (size_t)src * DDIM + c0;
#pragma unroll
            for (int j = 0; j < 8; ++j) {
                float4 v0 = *(const float4*)(tp + j * 8);
                float4 v1 = *(const float4*)(tp + j * 8 + 4);
                union { unsigned short u[8]; uint4 v; } o;
                o.u[0]=f2bf(v0.x); o.u[1]=f2bf(v0.y); o.u[2]=f2bf(v0.z); o.u[3]=f2bf(v0.w);
                o.u[4]=f2bf(v1.x); o.u[5]=f2bf(v1.y); o.u[6]=f2bf(v1.z); o.u[7]=f2bf(v1.w);
                const int g = (tid & 3) * 8 + j;
                *(uint4*)(Albs + r * 256 + (g ^ (r & 7)) * 8) = o.v;
            }
        } else {
            const unsigned short* ap = A + (size_t)(row0 + r) * DDIM + c0;
#pragma unroll
            for (int j = 0; j < 8; ++j) {
                union { unsigned short u[8]; uint4 v; } o;
                o.v = *(const uint4*)(ap + j * 8);
                if (AFFINE) {
#pragma unroll
                    for (int e = 0; e < 8; ++e) {
                        const int c = c0 + j * 8 + e;
                        o.u[e] = f2bf(fmaf(bf2f(o.u[e]), sc[c], sh[c]));
                    }
                }
                const int g = (tid & 3) * 8 + j;
                *(uint4*)(Albs + r * 256 + (g ^ (r & 7)) * 8) = o.v;
            }
        }
    }

    float bias_v[4];
#pragma unroll
    for (int nt = 0; nt < 4; ++nt)
        bias_v[nt] = bias[wn * 64 + nt * 16 + l15];

    floatx4 acc[4][4];
#pragma unroll
    for (int i = 0; i < 4; ++i)
#pragma unroll
        for (int j = 0; j < 4; ++j)
            acc[i][j] = floatx4{0.f, 0.f, 0.f, 0.f};

    __syncthreads();   // A panel visible to all waves

    // ---- K loop: manual 1-deep pipeline; B from global (L2-hot), A LDS ----
    const unsigned short* wb = Wt + (size_t)(wn * 64 + l15) * DDIM + quad * 8;
    short8 bfr[4], bnx[4], af[4], anx[4];
    {
        const int agp = (quad ^ (l15 & 7)) * 8;               // kk = 0
#pragma unroll
        for (int nt = 0; nt < 4; ++nt)
            bfr[nt] = *(const short8*)(wb + (size_t)(nt * 16) * DDIM);
#pragma unroll
        for (int mt = 0; mt < 4; ++mt)
            af[mt] = *(const short8*)(Albs + (mt * 16 + l15) * 256 + agp);
    }
#pragma unroll
    for (int kk = 0; kk < 8; ++kk) {
        if (kk < 7) {
            const int agp = (((kk + 1) * 4 + quad) ^ (l15 & 7)) * 8;
#pragma unroll
            for (int nt = 0; nt < 4; ++nt)
                bnx[nt] = *(const short8*)(wb + (size_t)(nt * 16) * DDIM
                                           + (kk + 1) * 32);
#pragma unroll
            for (int mt = 0; mt < 4; ++mt)
                anx[mt] = *(const short8*)(Albs + (mt * 16 + l15) * 256 + agp);
        }
#pragma unroll
        for (int mt = 0; mt < 4; ++mt)
#pragma unroll
            for (int nt = 0; nt < 4; ++nt)
                acc[mt][nt] = __builtin_amdgcn_mfma_f32_16x16x32_bf16(
                    af[mt], bfr[nt], acc[mt][nt], 0, 0, 0);
#pragma unroll
        for (int x = 0; x < 4; ++x) { af[x] = anx[x]; bfr[x] = bnx[x]; }
    }

    // ---- epilogue: bias + GELU + store (+ sharded column stats) ----
    float s1[4] = {0.f, 0.f, 0.f, 0.f};
    float s2[4] = {0.f, 0.f, 0.f, 0.f};
#pragma unroll
    for (int mt = 0; mt < 4; ++mt) {
        const int rb = row0 + mt * 16 + quad * 4;            // C/D row=quad*4+reg
#pragma unroll
        for (int nt = 0; nt < 4; ++nt) {
            const int col = wn * 64 + nt * 16 + l15;         // C/D col=lane&15
#pragma unroll
            for (int i = 0; i < 4; ++i) {
                float y = gelu_fast(acc[mt][nt][i] + bias_v[nt]);
                if (WRITE_F32) {
                    ((float*)outp)[(size_t)(rb + i) * DDIM + col] = y;
                } else {
                    ((unsigned short*)outp)[(size_t)(rb + i) * DDIM + col] = f2bf(y);
                }
                if (DO_STATS) { s1[nt] += y; s2[nt] += y * y; }
            }
        }
    }
    if (DO_STATS) {
#pragma unroll
        for (int nt = 0; nt < 4; ++nt) {   // reduce the 4 quads (same column)
            s1[nt] += __shfl_xor(s1[nt], 16); s1[nt] += __shfl_xor(s1[nt], 32);
            s2[nt] += __shfl_xor(s2[nt], 16); s2[nt] += __shfl_xor(s2[nt], 32);
        }
        float* sb = statShards + (blk & 7) * 512;            // 8-way shard
        if (quad == 0) {
#pragma unroll
            for (int nt = 0; nt < 4; ++nt) {
                const int col = wn * 64 + nt * 16 + l15;
                atomicAdd(&sb[col],       s1[nt]);
                atomicAdd(&sb[256 + col], s2[nt]);
            }
        }
    }
}

// ---------------------------------------------------------------------------
extern "C" void kernel_launch(void* const* d_in, const int* in_sizes, int n_in,
                              void* d_out, int out_size, void* d_ws, size_t ws_size,
                              hipStream_t stream)
{
    const int*   ids   = (const int*)  d_in[0];
    const float* table = (const float*)d_in[1];
    const float* W1 = (const float*)d_in[2];  const float* b1 = (const float*)d_in[3];
    const float* W2 = (const float*)d_in[4];  const float* b2 = (const float*)d_in[5];
    const float* W3 = (const float*)d_in[6];  const float* b3 = (const float*)d_in[7];
    const float* W4 = (const float*)d_in[8];  const float* b4 = (const float*)d_in[9];
    const float* g1 = (const float*)d_in[10]; const float* be1 = (const float*)d_in[11];
    const float* g2 = (const float*)d_in[12]; const float* be2 = (const float*)d_in[13];
    const float* g3 = (const float*)d_in[14]; const float* be3 = (const float*)d_in[15];

    unsigned char* ws = (unsigned char*)d_ws;
    unsigned short* Wt   = (unsigned short*)ws;                      // 512 KiB
    float* stats = (float*)(ws + (size_t)524288);                    // 48 KiB
    unsigned short* act1 = (unsigned short*)(ws + (size_t)1048576);  // 16 MiB
    unsigned short* act2 = (unsigned short*)(ws + (size_t)17825792); // 16 MiB
    unsigned short* Wt1 = Wt;
    unsigned short* Wt2 = Wt + 65536;
    unsigned short* Wt3 = Wt + 131072;
    unsigned short* Wt4 = Wt + 196608;

    prep_kernel<<<1024, 256, 0, stream>>>(W1, W2, W3, W4, Wt, stats);

    gemm_enc<1, 0, 0, 1><<<512, 256, 0, stream>>>(
        nullptr, ids, table, Wt1, b1, nullptr, nullptr, nullptr, act1, stats);
    gemm_enc<0, 1, 0, 1><<<512, 256, 0, stream>>>(
        act1, nullptr, nullptr, Wt2, b2, stats, g1, be1, act2, stats + 4096);
    gemm_enc<0, 1, 0, 1><<<512, 256, 0, stream>>>(
        act2, nullptr, nullptr, Wt3, b3, stats + 4096, g2, be2, act1, stats + 8192);
    gemm_enc<0, 1, 1, 0><<<512, 256, 0, stream>>>(
        act1, nullptr, nullptr, Wt4, b4, stats + 8192, g3, be3, (void*)d_out, nullptr);
}